// Round 5
// baseline (178.941 us; speedup 1.0000x reference)
//
#include <hip/hip_runtime.h>
#include <hip/hip_bf16.h>

#define N_EMBD 1024
#define T_SEQ  2048
#define BATCH  2
#define NHEAD  16
#define DKH    64
#define MTOK   (BATCH * T_SEQ)   // 4096

typedef __attribute__((ext_vector_type(8))) short short8;   // 8 x bf16
typedef __attribute__((ext_vector_type(4))) short short4v;  // 4 x bf16
typedef __attribute__((ext_vector_type(4))) float floatx4;  // MFMA C/D

#define QSCALE 0.18033688011112042f   // 0.125 * log2(e), folded into Q

static __device__ __forceinline__ short bf16_of(float f) {
    union { float f; unsigned u; } x; x.f = f;
    unsigned r = (x.u + 0x7fff + ((x.u >> 16) & 1)) >> 16;
    return (short)r;
}

// Fragment-major layout for a row-major [R][1024] bf16 matrix:
//   elem (row, k) -> ((row>>4)*32 + (k>>5))*512 + (((k>>3)&3)*16 + (row&15))*8 + (k&7)
// One MFMA operand fragment (16 rows x 32 k) = 512 contiguous shorts = 1KB,
// loadable as lane*16B fully-coalesced dwordx4.

// ---------------- fp32 -> bf16 fragment-major convert, all 5 tensors ----------------
__global__ __launch_bounds__(256) void cvt_frag(
    const float* __restrict__ x,  const float* __restrict__ Wq,
    const float* __restrict__ Wk, const float* __restrict__ Wv,
    const float* __restrict__ Wo,
    short* __restrict__ xf, short* __restrict__ wqkf,
    short* __restrict__ wvf, short* __restrict__ wof)
{
    int b = blockIdx.x;
    const float* src; short* dst; int srb, drb;
    if (b < 256)      { src = x;  dst = xf;   srb = b;       drb = srb; }
    else if (b < 320) { src = Wq; dst = wqkf; srb = b - 256; drb = srb; }
    else if (b < 384) { src = Wk; dst = wqkf; srb = b - 320; drb = srb + 64; }
    else if (b < 448) { src = Wv; dst = wvf;  srb = b - 384; drb = srb; }
    else              { src = Wo; dst = wof;  srb = b - 448; drb = srb; }

    const int row16 = threadIdx.x >> 4;          // 0..15
    const int kseg  = (threadIdx.x & 15) * 64;   // k base (64 elems per thread)
    const float* sp = src + ((long)srb * 16 + row16) * 1024 + kseg;
    short* dp       = dst + ((long)drb * 32 + (kseg >> 5)) * 512 + row16 * 8;

#pragma unroll
    for (int c = 0; c < 8; ++c) {
        float4 v0 = *(const float4*)(sp + c * 8);
        float4 v1 = *(const float4*)(sp + c * 8 + 4);
        short8 o;
        o[0] = bf16_of(v0.x); o[1] = bf16_of(v0.y); o[2] = bf16_of(v0.z); o[3] = bf16_of(v0.w);
        o[4] = bf16_of(v1.x); o[5] = bf16_of(v1.y); o[6] = bf16_of(v1.z); o[7] = bf16_of(v1.w);
        *(short8*)(dp + (c >> 2) * 512 + (c & 3) * 128) = o;
    }
}

// K-loop: per-wave 64x128 tile, register ping-pong prefetch, no LDS/barriers.
// (R0-verbatim; used by gemm_proj.)
#define GEMM_KLOOP(Ab, Bb)                                                     \
    floatx4 acc[4][8] = {};                                                    \
    short8 a0[4], a1[4], b0[8], b1[8];                                         \
    _Pragma("unroll") for (int i = 0; i < 4; ++i)                              \
        a0[i] = *(const short8*)(Ab + (long)i * 32 * 512);                     \
    _Pragma("unroll") for (int j = 0; j < 8; ++j)                              \
        b0[j] = *(const short8*)(Bb + (long)j * 32 * 512);                     \
    for (int kc = 0; kc < 32; kc += 2) {                                       \
        _Pragma("unroll") for (int i = 0; i < 4; ++i)                          \
            a1[i] = *(const short8*)(Ab + ((long)i * 32 + kc + 1) * 512);      \
        _Pragma("unroll") for (int j = 0; j < 8; ++j)                          \
            b1[j] = *(const short8*)(Bb + ((long)j * 32 + kc + 1) * 512);      \
        _Pragma("unroll") for (int i = 0; i < 4; ++i)                          \
            _Pragma("unroll") for (int j = 0; j < 8; ++j)                      \
                acc[i][j] = __builtin_amdgcn_mfma_f32_16x16x32_bf16(           \
                    a0[i], b0[j], acc[i][j], 0, 0, 0);                         \
        if (kc + 2 < 32) {                                                     \
            _Pragma("unroll") for (int i = 0; i < 4; ++i)                      \
                a0[i] = *(const short8*)(Ab + ((long)i * 32 + kc + 2) * 512);  \
            _Pragma("unroll") for (int j = 0; j < 8; ++j)                      \
                b0[j] = *(const short8*)(Bb + ((long)j * 32 + kc + 2) * 512);  \
        }                                                                      \
        _Pragma("unroll") for (int i = 0; i < 4; ++i)                          \
            _Pragma("unroll") for (int j = 0; j < 8; ++j)                      \
                acc[i][j] = __builtin_amdgcn_mfma_f32_16x16x32_bf16(           \
                    a1[i], b1[j], acc[i][j], 0, 0, 0);                         \
    }

// 64x64 variant: half the per-wave tile -> half the register state ->
// 2x the co-resident waves (TLP latency hiding). Used by gemm_qkv.
#define GEMM_KLOOP64(Ab, Bb)                                                   \
    floatx4 acc[4][4] = {};                                                    \
    short8 a0[4], a1[4], b0[4], b1[4];                                         \
    _Pragma("unroll") for (int i = 0; i < 4; ++i)                              \
        a0[i] = *(const short8*)(Ab + (long)i * 32 * 512);                     \
    _Pragma("unroll") for (int j = 0; j < 4; ++j)                              \
        b0[j] = *(const short8*)(Bb + (long)j * 32 * 512);                     \
    for (int kc = 0; kc < 32; kc += 2) {                                       \
        _Pragma("unroll") for (int i = 0; i < 4; ++i)                          \
            a1[i] = *(const short8*)(Ab + ((long)i * 32 + kc + 1) * 512);      \
        _Pragma("unroll") for (int j = 0; j < 4; ++j)                          \
            b1[j] = *(const short8*)(Bb + ((long)j * 32 + kc + 1) * 512);      \
        _Pragma("unroll") for (int i = 0; i < 4; ++i)                          \
            _Pragma("unroll") for (int j = 0; j < 4; ++j)                      \
                acc[i][j] = __builtin_amdgcn_mfma_f32_16x16x32_bf16(           \
                    a0[i], b0[j], acc[i][j], 0, 0, 0);                         \
        if (kc + 2 < 32) {                                                     \
            _Pragma("unroll") for (int i = 0; i < 4; ++i)                      \
                a0[i] = *(const short8*)(Ab + ((long)i * 32 + kc + 2) * 512);  \
            _Pragma("unroll") for (int j = 0; j < 4; ++j)                      \
                b0[j] = *(const short8*)(Bb + ((long)j * 32 + kc + 2) * 512);  \
        }                                                                      \
        _Pragma("unroll") for (int i = 0; i < 4; ++i)                          \
            _Pragma("unroll") for (int j = 0; j < 4; ++j)                      \
                acc[i][j] = __builtin_amdgcn_mfma_f32_16x16x32_bf16(           \
                    a1[i], b1[j], acc[i][j], 0, 0, 0);                         \
    }

// ---------------- QKV GEMM: 3072 single-wave 64x64 blocks, no LDS ----------------
// bid < 2048: Q/K transposed. M=2048 ([Wq;Wk] features): mt=bid>>6 (0..31);
//             N=4096 (tokens): nt=bid&63 (0..63).
// bid >= 2048: V normal. M=4096 (tokens): mt=v>>4 (0..63);
//              N=1024 (Wv features): nt=v&15 (0..15).
// 3072 waves / 1024 SIMDs = 3 waves/SIMD co-resident (vs 1.5 at 64x128).
__global__ __launch_bounds__(64, 3) void gemm_qkv(
    const short* __restrict__ xf, const short* __restrict__ wqkf,
    const short* __restrict__ wvf,
    const float* __restrict__ bq, const float* __restrict__ bk, const float* __restrict__ bv,
    short* __restrict__ outQ, short* __restrict__ outK, short* __restrict__ outV)
{
    const int lane = threadIdx.x & 63;
    const int quad = lane >> 4, lr = lane & 15;
    const int wid  = blockIdx.x;
    const bool isQK = wid < 2048;
    int mw, nw;
    const short *Af, *Bf;
    if (isQK) { mw = (wid >> 6) * 64;          nw = (wid & 63) * 64;  Af = wqkf; Bf = xf; }
    else      { int v = wid - 2048;
                mw = (v >> 4) * 64;            nw = (v & 15) * 64;    Af = xf;   Bf = wvf; }

    const short* Ab = Af + (long)(mw >> 4) * 32 * 512 + lane * 8;
    const short* Bb = Bf + (long)(nw >> 4) * 32 * 512 + lane * 8;

    GEMM_KLOOP64(Ab, Bb)

    if (isQK) {
#pragma unroll
        for (int i = 0; i < 4; ++i) {
#pragma unroll
            for (int j = 0; j < 4; ++j) {
                int f0  = mw + i * 16 + quad * 4;      // feature of [Wq;Wk]
                int t   = nw + j * 16 + lr;            // global token
                int tb  = t & 2047;
                int sel = f0 >> 10;                    // 0=Q, 1=K
                int fb  = f0 & 1023;
                int h   = fb >> 6, d0 = fb & 63;
                long bh = (long)(t >> 11) * NHEAD + h;
                float4 bias = *(const float4*)((sel ? bk : bq) + fb);
                short4v y;
#pragma unroll
                for (int r = 0; r < 4; ++r) {
                    float v = acc[i][j][r] + (&bias.x)[r];
                    if (sel == 0) v *= QSCALE;
                    y[r] = bf16_of(v);
                }
                long idx = ((bh * 128 + (tb >> 4)) * 2 + (d0 >> 5)) * 512
                         + (((d0 >> 3) & 3) * 16 + (tb & 15)) * 8 + (d0 & 7);
                *(short4v*)((sel ? outK : outQ) + idx) = y;
            }
        }
    } else {
#pragma unroll
        for (int i = 0; i < 4; ++i) {
#pragma unroll
            for (int j = 0; j < 4; ++j) {
                int t0 = mw + i * 16 + quad * 4;       // global token base
                int tb = t0 & 2047;
                int d  = nw + j * 16 + lr;             // Wv feature
                int h  = d >> 6, dblk = (d >> 4) & 3;
                long bh = (long)(t0 >> 11) * NHEAD + h;
                float bias = bv[d];
                short4v y;
#pragma unroll
                for (int r = 0; r < 4; ++r) y[r] = bf16_of(acc[i][j][r] + bias);
                long idx = ((bh * 64 + (tb >> 5)) * 4 + dblk) * 512
                         + lane * 8 + (i & 1) * 4;
                *(short4v*)(outV + idx) = y;
            }
        }
    }
}

// ---------------- output projection: 512 single-wave blocks, no LDS (R0) ----------------
// Transposed (rows = out-feature 64, cols = token 128); float4 stores.
__global__ __launch_bounds__(64, 2) void gemm_proj(
    const short* __restrict__ Yf, const short* __restrict__ wof,
    const float* __restrict__ bo, float* __restrict__ out)
{
    const int lane = threadIdx.x & 63;
    const int quad = lane >> 4, lr = lane & 15;
    const int wid  = blockIdx.x;
    const int mw   = (wid >> 5) * 64;     // out-feature
    const int nw   = (wid & 31) * 128;    // token

    const short* Ab = wof + (long)(mw >> 4) * 32 * 512 + lane * 8;
    const short* Bb = Yf  + (long)(nw >> 4) * 32 * 512 + lane * 8;

    GEMM_KLOOP(Ab, Bb)

#pragma unroll
    for (int i = 0; i < 4; ++i) {
#pragma unroll
        for (int j = 0; j < 8; ++j) {
            int  f0 = mw + i * 16 + quad * 4;
            long t  = nw + j * 16 + lr;
            float4 b4 = *(const float4*)(bo + f0);
            float4 o4;
            o4.x = acc[i][j][0] + b4.x;
            o4.y = acc[i][j][1] + b4.y;
            o4.z = acc[i][j][2] + b4.z;
            o4.w = acc[i][j][3] + b4.w;
            *(float4*)(out + t * N_EMBD + f0) = o4;
        }
    }
}

// ---------------- flash attention (R0 core) + setprio around MFMA clusters ----------------
__global__ __launch_bounds__(256) void attn_kernel(
    const short* __restrict__ Qf, const short* __restrict__ Kf,
    const short* __restrict__ Vf, short* __restrict__ Y)
{
    __shared__ float Ob[2][32][68];
    __shared__ float Lb[2][32];

    const int tid  = threadIdx.x;
    const int w    = tid >> 6, lane = tid & 63;
    const int quad = lane >> 4, lr = lane & 15;
    const int qs   = w & 1, half = w >> 1;

    const int id = blockIdx.x;
    const int qt = 31 - (id >> 5);
    const int bh = id & 31;

    const short* Qp = Qf + (long)bh * 131072;
    const short* Kp = Kf + (long)bh * 131072;
    const short* Vp = Vf + (long)bh * 131072;

    const int qrb = qt * 64 + qs * 32;
    const int qb  = qrb >> 4;

    short8 qfv[2][2];
#pragma unroll
    for (int m = 0; m < 2; ++m)
#pragma unroll
        for (int c = 0; c < 2; ++c)
            qfv[m][c] = *(const short8*)(Qp + (long)(((qb + m) * 2 + c) * 512) + lane * 8);

    floatx4 o[2][4] = {};
    float rs[2] = {0.f, 0.f};

    const int S_tot = 2 * qt + qs + 1;
    const int h0 = (S_tot + 1) >> 1;
    const int sb = half ? h0 : 0;
    const int se = half ? S_tot : h0;

    short8 kbn[2][2];
    if (sb < se) {
#pragma unroll
        for (int blk = 0; blk < 2; ++blk)
#pragma unroll
            for (int c = 0; c < 2; ++c)
                kbn[blk][c] = *(const short8*)(Kp + (long)(((sb * 2 + blk) * 2 + c) * 512) + lane * 8);
    }

    for (int s = sb; s < se; ++s) {
        short8 ka[2][2];
#pragma unroll
        for (int blk = 0; blk < 2; ++blk)
#pragma unroll
            for (int c = 0; c < 2; ++c) ka[blk][c] = kbn[blk][c];
        if (s + 1 < se) {
#pragma unroll
            for (int blk = 0; blk < 2; ++blk)
#pragma unroll
                for (int c = 0; c < 2; ++c)
                    kbn[blk][c] = *(const short8*)(Kp + (long)((((s + 1) * 2 + blk) * 2 + c) * 512) + lane * 8);
        }
        short8 va[4];
#pragma unroll
        for (int d = 0; d < 4; ++d)
            va[d] = *(const short8*)(Vp + (long)((s * 4 + d) * 512) + lane * 8);

        floatx4 sc[2][2];
        __builtin_amdgcn_s_setprio(1);
#pragma unroll
        for (int m = 0; m < 2; ++m)
#pragma unroll
            for (int blk = 0; blk < 2; ++blk) {
                floatx4 z = {};
                z = __builtin_amdgcn_mfma_f32_16x16x32_bf16(ka[blk][0], qfv[m][0], z, 0, 0, 0);
                z = __builtin_amdgcn_mfma_f32_16x16x32_bf16(ka[blk][1], qfv[m][1], z, 0, 0, 0);
                sc[m][blk] = z;
            }
        __builtin_amdgcn_s_setprio(0);

        if (s == S_tot - 1) {
            const int k0 = s * 32;
#pragma unroll
            for (int m = 0; m < 2; ++m)
#pragma unroll
                for (int blk = 0; blk < 2; ++blk)
#pragma unroll
                    for (int r = 0; r < 4; ++r) {
                        int key = k0 + blk * 16 + quad * 4 + r;
                        if (key > qrb + m * 16 + lr) sc[m][blk][r] = -INFINITY;
                    }
        }

        short8 pa[2];
#pragma unroll
        for (int m = 0; m < 2; ++m) {
            union { short8 v; short e[8]; } pu;
#pragma unroll
            for (int blk = 0; blk < 2; ++blk)
#pragma unroll
                for (int r = 0; r < 4; ++r) {
                    float p = __builtin_amdgcn_exp2f(sc[m][blk][r]);
                    rs[m] += p;
                    union { float f; unsigned u; } cc; cc.f = p;
                    pu.e[blk * 4 + r] = (short)((cc.u + 0x8000u) >> 16);
                }
            pa[m] = pu.v;
        }

        __builtin_amdgcn_s_setprio(1);
#pragma unroll
        for (int m = 0; m < 2; ++m)
#pragma unroll
            for (int d = 0; d < 4; ++d)
                o[m][d] = __builtin_amdgcn_mfma_f32_16x16x32_bf16(va[d], pa[m], o[m][d], 0, 0, 0);
        __builtin_amdgcn_s_setprio(0);
    }

#pragma unroll
    for (int m = 0; m < 2; ++m) {
        rs[m] += __shfl_xor(rs[m], 16, 64);
        rs[m] += __shfl_xor(rs[m], 32, 64);
    }

    if (half == 1) {
#pragma unroll
        for (int m = 0; m < 2; ++m) {
#pragma unroll
            for (int d = 0; d < 4; ++d)
                *(floatx4*)&Ob[qs][m * 16 + lr][d * 16 + quad * 4] = o[m][d];
            Lb[qs][m * 16 + lr] = rs[m];
        }
    }
    __syncthreads();
    if (half == 0) {
        // write Y fragment-major over GLOBAL tokens: rowblk = (bh>>4)*128 + qb + m
        const long rb0 = (long)(bh >> 4) * 128 + qb;
        const int  hk  = (bh & 15) * DKH;           // k base for this head
#pragma unroll
        for (int m = 0; m < 2; ++m) {
            float l   = rs[m] + Lb[qs][m * 16 + lr];
            float inv = 1.f / l;
            long  rb  = rb0 + m;
#pragma unroll
            for (int d = 0; d < 4; ++d) {
                floatx4 ob = *(const floatx4*)&Ob[qs][m * 16 + lr][d * 16 + quad * 4];
                short4v y4;
#pragma unroll
                for (int r = 0; r < 4; ++r) y4[r] = bf16_of((o[m][d][r] + ob[r]) * inv);
                int kb = hk + d * 16 + quad * 4;
                long idx = (rb * 32 + (kb >> 5)) * 512
                         + (((kb >> 3) & 3) * 16 + lr) * 8 + (quad & 1) * 4;
                *(short4v*)(Y + idx) = y4;
            }
        }
    }
}

extern "C" void kernel_launch(void* const* d_in, const int* in_sizes, int n_in,
                              void* d_out, int out_size, void* d_ws, size_t ws_size,
                              hipStream_t stream) {
    const float* x  = (const float*)d_in[0];
    const float* Wq = (const float*)d_in[1];
    const float* bq = (const float*)d_in[2];
    const float* Wk = (const float*)d_in[3];
    const float* bk = (const float*)d_in[4];
    const float* Wv = (const float*)d_in[5];
    const float* bv = (const float*)d_in[6];
    const float* Wo = (const float*)d_in[7];
    const float* bo = (const float*)d_in[8];
    float* out = (float*)d_out;

    char* ws = (char*)d_ws;
    short* xf   = (short*)(ws);                      // x frag-major, 8MB; reused as Yf
    short* wqkf = (short*)(ws + (8L  << 20));        // [Wq;Wk] frag-major, 4MB
    short* wvf  = (short*)(ws + (12L << 20));        // Wv frag-major, 2MB
    short* wof  = (short*)(ws + (14L << 20));        // Wo frag-major, 2MB
    short* Qb   = (short*)(ws + (16L << 20));        // Qf, 8MB (pre-scaled)
    short* Kbuf = (short*)(ws + (24L << 20));        // Kf, 8MB
    short* Vtb  = (short*)(ws + (32L << 20));        // Vf, 8MB
    short* Yf   = xf;                                // reuse (x dead after QKV GEMM)

    cvt_frag<<<512, 256, 0, stream>>>(x, Wq, Wk, Wv, Wo, xf, wqkf, wvf, wof);

    gemm_qkv<<<3072, 64, 0, stream>>>(xf, wqkf, wvf, bq, bk, bv, Qb, Kbuf, Vtb);
    attn_kernel<<<1024, 256, 0, stream>>>(Qb, Kbuf, Vtb, Yf);
    gemm_proj<<<512, 64, 0, stream>>>(Yf, wof, bo, out);
}

// Round 6
// 178.709 us; speedup vs baseline: 1.0013x; 1.0013x over previous
//
#include <hip/hip_runtime.h>
#include <hip/hip_bf16.h>

#define N_EMBD 1024
#define T_SEQ  2048
#define BATCH  2
#define NHEAD  16
#define DKH    64
#define MTOK   (BATCH * T_SEQ)   // 4096

typedef __attribute__((ext_vector_type(8))) short short8;   // 8 x bf16
typedef __attribute__((ext_vector_type(4))) short short4v;  // 4 x bf16
typedef __attribute__((ext_vector_type(4))) float floatx4;  // MFMA C/D

#define QSCALE 0.18033688011112042f   // 0.125 * log2(e), folded into Q

static __device__ __forceinline__ short bf16_of(float f) {
    union { float f; unsigned u; } x; x.f = f;
    unsigned r = (x.u + 0x7fff + ((x.u >> 16) & 1)) >> 16;
    return (short)r;
}

// async global->LDS, 16B per lane; LDS dest is wave-uniform base + lane*16
static __device__ __forceinline__ void gload16(const short* g, short* l) {
    __builtin_amdgcn_global_load_lds(
        (const __attribute__((address_space(1))) unsigned int*)(g),
        (__attribute__((address_space(3))) unsigned int*)(l),
        16, 0, 0);
}

// Fragment-major layout for a row-major [R][1024] bf16 matrix:
//   elem (row, k) -> ((row>>4)*32 + (k>>5))*512 + (((k>>3)&3)*16 + (row&15))*8 + (k&7)
// One MFMA operand fragment (16 rows x 32 k) = 512 contiguous shorts = 1KB,
// loadable as lane*16B fully-coalesced dwordx4 (and by one global_load_lds).

// ---------------- fp32 -> bf16 fragment-major convert, all 5 tensors ----------------
__global__ __launch_bounds__(256) void cvt_frag(
    const float* __restrict__ x,  const float* __restrict__ Wq,
    const float* __restrict__ Wk, const float* __restrict__ Wv,
    const float* __restrict__ Wo,
    short* __restrict__ xf, short* __restrict__ wqkf,
    short* __restrict__ wvf, short* __restrict__ wof)
{
    int b = blockIdx.x;
    const float* src; short* dst; int srb, drb;
    if (b < 256)      { src = x;  dst = xf;   srb = b;       drb = srb; }
    else if (b < 320) { src = Wq; dst = wqkf; srb = b - 256; drb = srb; }
    else if (b < 384) { src = Wk; dst = wqkf; srb = b - 320; drb = srb + 64; }
    else if (b < 448) { src = Wv; dst = wvf;  srb = b - 384; drb = srb; }
    else              { src = Wo; dst = wof;  srb = b - 448; drb = srb; }

    const int row16 = threadIdx.x >> 4;          // 0..15
    const int kseg  = (threadIdx.x & 15) * 64;   // k base (64 elems per thread)
    const float* sp = src + ((long)srb * 16 + row16) * 1024 + kseg;
    short* dp       = dst + ((long)drb * 32 + (kseg >> 5)) * 512 + row16 * 8;

#pragma unroll
    for (int c = 0; c < 8; ++c) {
        float4 v0 = *(const float4*)(sp + c * 8);
        float4 v1 = *(const float4*)(sp + c * 8 + 4);
        short8 o;
        o[0] = bf16_of(v0.x); o[1] = bf16_of(v0.y); o[2] = bf16_of(v0.z); o[3] = bf16_of(v0.w);
        o[4] = bf16_of(v1.x); o[5] = bf16_of(v1.y); o[6] = bf16_of(v1.z); o[7] = bf16_of(v1.w);
        *(short8*)(dp + (c >> 2) * 512 + (c & 3) * 128) = o;
    }
}

// ---- R0 K-loop: per-wave 64x128 tile, register ping-pong, no LDS (proj) ----
#define GEMM_KLOOP(Ab, Bb)                                                     \
    floatx4 acc[4][8] = {};                                                    \
    short8 a0[4], a1[4], b0[8], b1[8];                                         \
    _Pragma("unroll") for (int i = 0; i < 4; ++i)                              \
        a0[i] = *(const short8*)(Ab + (long)i * 32 * 512);                     \
    _Pragma("unroll") for (int j = 0; j < 8; ++j)                              \
        b0[j] = *(const short8*)(Bb + (long)j * 32 * 512);                     \
    for (int kc = 0; kc < 32; kc += 2) {                                       \
        _Pragma("unroll") for (int i = 0; i < 4; ++i)                          \
            a1[i] = *(const short8*)(Ab + ((long)i * 32 + kc + 1) * 512);      \
        _Pragma("unroll") for (int j = 0; j < 8; ++j)                          \
            b1[j] = *(const short8*)(Bb + ((long)j * 32 + kc + 1) * 512);      \
        _Pragma("unroll") for (int i = 0; i < 4; ++i)                          \
            _Pragma("unroll") for (int j = 0; j < 8; ++j)                      \
                acc[i][j] = __builtin_amdgcn_mfma_f32_16x16x32_bf16(           \
                    a0[i], b0[j], acc[i][j], 0, 0, 0);                         \
        if (kc + 2 < 32) {                                                     \
            _Pragma("unroll") for (int i = 0; i < 4; ++i)                      \
                a0[i] = *(const short8*)(Ab + ((long)i * 32 + kc + 2) * 512);  \
            _Pragma("unroll") for (int j = 0; j < 8; ++j)                      \
                b0[j] = *(const short8*)(Bb + ((long)j * 32 + kc + 2) * 512);  \
        }                                                                      \
        _Pragma("unroll") for (int i = 0; i < 4; ++i)                          \
            _Pragma("unroll") for (int j = 0; j < 8; ++j)                      \
                acc[i][j] = __builtin_amdgcn_mfma_f32_16x16x32_bf16(           \
                    a1[i], b1[j], acc[i][j], 0, 0, 0);                         \
    }

// ---- R4 deep-pipelined LDS K-loop (T4 counted vmcnt), 128x128 tile, 4 waves,
// 3 x 16KB LDS buffers, 2-steps-ahead prefetch, vmcnt(4) steady state.
// Halves cache-side traffic vs register streaming (per-CU L1-return-BW bound).
#define LDS_KLOOP(AfP, BfP, rb0, cb0)                                           \
    __shared__ short lds[3][16 * 512];                                          \
    floatx4 acc[4][4] = {};                                                     \
    {                                                                           \
        const int w_    = threadIdx.x >> 6;                                     \
        const int lane_ = threadIdx.x & 63;                                     \
        const int wr_   = w_ >> 1, wc_ = w_ & 1;                                \
        const short* gb = (w_ < 2                                               \
            ? (AfP) + (long)((rb0) + w_ * 4) * 32 * 512                         \
            : (BfP) + (long)((cb0) + (w_ - 2) * 4) * 32 * 512) + lane_ * 8;     \
        short* p0 = &lds[0][w_ * 4 * 512];                                      \
        short* p1 = &lds[1][w_ * 4 * 512];                                      \
        short* p2 = &lds[2][w_ * 4 * 512];                                      \
        const int lo_a = (wr_ * 4) * 512 + lane_ * 8 - w_ * 4 * 512;            \
        const int lo_b = (8 + wc_ * 4) * 512 + lane_ * 8 - w_ * 4 * 512;        \
        _Pragma("unroll") for (int f = 0; f < 4; ++f)                           \
            gload16(gb + (long)f * 32 * 512, p0 + f * 512);                     \
        _Pragma("unroll") for (int f = 0; f < 4; ++f)                           \
            gload16(gb + ((long)f * 32 + 1) * 512, p1 + f * 512);               \
        for (int kb = 0; kb < 32; ++kb) {                                       \
            if (kb < 31) asm volatile("s_waitcnt vmcnt(4)" ::: "memory");       \
            else         asm volatile("s_waitcnt vmcnt(0)" ::: "memory");       \
            __syncthreads();                                                    \
            if (kb + 2 < 32) {                                                  \
                _Pragma("unroll") for (int f = 0; f < 4; ++f)                   \
                    gload16(gb + ((long)f * 32 + kb + 2) * 512, p2 + f * 512);  \
            }                                                                   \
            short8 a_[4], b_[4];                                                \
            _Pragma("unroll") for (int i = 0; i < 4; ++i)                       \
                a_[i] = *(const short8*)(p0 + lo_a + i * 512);                  \
            _Pragma("unroll") for (int j = 0; j < 4; ++j)                       \
                b_[j] = *(const short8*)(p0 + lo_b + j * 512);                  \
            _Pragma("unroll") for (int i = 0; i < 4; ++i)                       \
                _Pragma("unroll") for (int j = 0; j < 4; ++j)                   \
                    acc[i][j] = __builtin_amdgcn_mfma_f32_16x16x32_bf16(        \
                        a_[i], b_[j], acc[i][j], 0, 0, 0);                      \
            short* t_ = p0; p0 = p1; p1 = p2; p2 = t_;                          \
        }                                                                       \
    }

// ---------------- QKV GEMM: 768 four-wave 128x128 blocks, LDS-staged (R4) ----------------
// bid < 512: Q/K transposed. M=2048 ([Wq;Wk] features), N=4096 (tokens).
// bid >= 512: V normal. M=4096 (tokens), N=1024 (Wv features).
__global__ __launch_bounds__(256) void gemm_qkv(
    const short* __restrict__ xf, const short* __restrict__ wqkf,
    const short* __restrict__ wvf,
    const float* __restrict__ bq, const float* __restrict__ bk, const float* __restrict__ bv,
    short* __restrict__ outQ, short* __restrict__ outK, short* __restrict__ outV)
{
    const int lane = threadIdx.x & 63;
    const int w    = threadIdx.x >> 6;
    const int quad = lane >> 4, lr = lane & 15;
    const int wr   = w >> 1, wc = w & 1;

    const int bid  = blockIdx.x;
    const bool isQK = bid < 512;
    int mt, nt;
    const short *Af, *Bf;
    if (isQK) { mt = bid >> 5;        nt = bid & 31; Af = wqkf; Bf = xf; }
    else      { int v = bid - 512;
                mt = v >> 3;          nt = v & 7;    Af = xf;   Bf = wvf; }

    const int rb0 = mt * 8;           // A rowblk base
    const int cb0 = nt * 8;           // B rowblk base
    const int mwv = mt * 128 + wr * 64;   // this wave's output row base
    const int nwv = nt * 128 + wc * 64;   // this wave's output col base

    LDS_KLOOP(Af, Bf, rb0, cb0)

    if (isQK) {
#pragma unroll
        for (int i = 0; i < 4; ++i) {
#pragma unroll
            for (int j = 0; j < 4; ++j) {
                int f0  = mwv + i * 16 + quad * 4;     // feature of [Wq;Wk]
                int t   = nwv + j * 16 + lr;           // global token
                int tb  = t & 2047;
                int sel = f0 >> 10;                    // 0=Q, 1=K
                int fb  = f0 & 1023;
                int h   = fb >> 6, d0 = fb & 63;
                long bh = (long)(t >> 11) * NHEAD + h;
                float4 bias = *(const float4*)((sel ? bk : bq) + fb);
                short4v y;
#pragma unroll
                for (int r = 0; r < 4; ++r) {
                    float v = acc[i][j][r] + (&bias.x)[r];
                    if (sel == 0) v *= QSCALE;
                    y[r] = bf16_of(v);
                }
                long idx = ((bh * 128 + (tb >> 4)) * 2 + (d0 >> 5)) * 512
                         + (((d0 >> 3) & 3) * 16 + (tb & 15)) * 8 + (d0 & 7);
                *(short4v*)((sel ? outK : outQ) + idx) = y;
            }
        }
    } else {
#pragma unroll
        for (int i = 0; i < 4; ++i) {
#pragma unroll
            for (int j = 0; j < 4; ++j) {
                int t0 = mwv + i * 16 + quad * 4;      // global token base
                int tb = t0 & 2047;
                int d  = nwv + j * 16 + lr;            // Wv feature
                int h  = d >> 6, dblk = (d >> 4) & 3;
                long bh = (long)(t0 >> 11) * NHEAD + h;
                float bias = bv[d];
                short4v y;
#pragma unroll
                for (int r = 0; r < 4; ++r) y[r] = bf16_of(acc[i][j][r] + bias);
                long idx = ((bh * 64 + (tb >> 5)) * 4 + dblk) * 512
                         + lane * 8 + (i & 1) * 4;
                *(short4v*)(outV + idx) = y;
            }
        }
    }
}

// ---------------- output projection: 512 single-wave blocks, no LDS (R0) ----------------
// Transposed (rows = out-feature 64, cols = token 128); float4 stores.
__global__ __launch_bounds__(64, 2) void gemm_proj(
    const short* __restrict__ Yf, const short* __restrict__ wof,
    const float* __restrict__ bo, float* __restrict__ out)
{
    const int lane = threadIdx.x & 63;
    const int quad = lane >> 4, lr = lane & 15;
    const int wid  = blockIdx.x;
    const int mw   = (wid >> 5) * 64;     // out-feature
    const int nw   = (wid & 31) * 128;    // token

    const short* Ab = wof + (long)(mw >> 4) * 32 * 512 + lane * 8;
    const short* Bb = Yf  + (long)(nw >> 4) * 32 * 512 + lane * 8;

    GEMM_KLOOP(Ab, Bb)

#pragma unroll
    for (int i = 0; i < 4; ++i) {
#pragma unroll
        for (int j = 0; j < 8; ++j) {
            int  f0 = mw + i * 16 + quad * 4;
            long t  = nw + j * 16 + lr;
            float4 b4 = *(const float4*)(bo + f0);
            float4 o4;
            o4.x = acc[i][j][0] + b4.x;
            o4.y = acc[i][j][1] + b4.y;
            o4.z = acc[i][j][2] + b4.z;
            o4.w = acc[i][j][3] + b4.w;
            *(float4*)(out + t * N_EMBD + f0) = o4;
        }
    }
}

// ---------------- flash attention (R0 core) + setprio around MFMA clusters ----------------
__global__ __launch_bounds__(256) void attn_kernel(
    const short* __restrict__ Qf, const short* __restrict__ Kf,
    const short* __restrict__ Vf, short* __restrict__ Y)
{
    __shared__ float Ob[2][32][68];
    __shared__ float Lb[2][32];

    const int tid  = threadIdx.x;
    const int w    = tid >> 6, lane = tid & 63;
    const int quad = lane >> 4, lr = lane & 15;
    const int qs   = w & 1, half = w >> 1;

    const int id = blockIdx.x;
    const int qt = 31 - (id >> 5);
    const int bh = id & 31;

    const short* Qp = Qf + (long)bh * 131072;
    const short* Kp = Kf + (long)bh * 131072;
    const short* Vp = Vf + (long)bh * 131072;

    const int qrb = qt * 64 + qs * 32;
    const int qb  = qrb >> 4;

    short8 qfv[2][2];
#pragma unroll
    for (int m = 0; m < 2; ++m)
#pragma unroll
        for (int c = 0; c < 2; ++c)
            qfv[m][c] = *(const short8*)(Qp + (long)(((qb + m) * 2 + c) * 512) + lane * 8);

    floatx4 o[2][4] = {};
    float rs[2] = {0.f, 0.f};

    const int S_tot = 2 * qt + qs + 1;
    const int h0 = (S_tot + 1) >> 1;
    const int sb = half ? h0 : 0;
    const int se = half ? S_tot : h0;

    short8 kbn[2][2];
    if (sb < se) {
#pragma unroll
        for (int blk = 0; blk < 2; ++blk)
#pragma unroll
            for (int c = 0; c < 2; ++c)
                kbn[blk][c] = *(const short8*)(Kp + (long)(((sb * 2 + blk) * 2 + c) * 512) + lane * 8);
    }

    for (int s = sb; s < se; ++s) {
        short8 ka[2][2];
#pragma unroll
        for (int blk = 0; blk < 2; ++blk)
#pragma unroll
            for (int c = 0; c < 2; ++c) ka[blk][c] = kbn[blk][c];
        if (s + 1 < se) {
#pragma unroll
            for (int blk = 0; blk < 2; ++blk)
#pragma unroll
                for (int c = 0; c < 2; ++c)
                    kbn[blk][c] = *(const short8*)(Kp + (long)((((s + 1) * 2 + blk) * 2 + c) * 512) + lane * 8);
        }
        short8 va[4];
#pragma unroll
        for (int d = 0; d < 4; ++d)
            va[d] = *(const short8*)(Vp + (long)((s * 4 + d) * 512) + lane * 8);

        floatx4 sc[2][2];
        __builtin_amdgcn_s_setprio(1);
#pragma unroll
        for (int m = 0; m < 2; ++m)
#pragma unroll
            for (int blk = 0; blk < 2; ++blk) {
                floatx4 z = {};
                z = __builtin_amdgcn_mfma_f32_16x16x32_bf16(ka[blk][0], qfv[m][0], z, 0, 0, 0);
                z = __builtin_amdgcn_mfma_f32_16x16x32_bf16(ka[blk][1], qfv[m][1], z, 0, 0, 0);
                sc[m][blk] = z;
            }
        __builtin_amdgcn_s_setprio(0);

        if (s == S_tot - 1) {
            const int k0 = s * 32;
#pragma unroll
            for (int m = 0; m < 2; ++m)
#pragma unroll
                for (int blk = 0; blk < 2; ++blk)
#pragma unroll
                    for (int r = 0; r < 4; ++r) {
                        int key = k0 + blk * 16 + quad * 4 + r;
                        if (key > qrb + m * 16 + lr) sc[m][blk][r] = -INFINITY;
                    }
        }

        short8 pa[2];
#pragma unroll
        for (int m = 0; m < 2; ++m) {
            union { short8 v; short e[8]; } pu;
#pragma unroll
            for (int blk = 0; blk < 2; ++blk)
#pragma unroll
                for (int r = 0; r < 4; ++r) {
                    float p = __builtin_amdgcn_exp2f(sc[m][blk][r]);
                    rs[m] += p;
                    union { float f; unsigned u; } cc; cc.f = p;
                    pu.e[blk * 4 + r] = (short)((cc.u + 0x8000u) >> 16);
                }
            pa[m] = pu.v;
        }

        __builtin_amdgcn_s_setprio(1);
#pragma unroll
        for (int m = 0; m < 2; ++m)
#pragma unroll
            for (int d = 0; d < 4; ++d)
                o[m][d] = __builtin_amdgcn_mfma_f32_16x16x32_bf16(va[d], pa[m], o[m][d], 0, 0, 0);
        __builtin_amdgcn_s_setprio(0);
    }

#pragma unroll
    for (int m = 0; m < 2; ++m) {
        rs[m] += __shfl_xor(rs[m], 16, 64);
        rs[m] += __shfl_xor(rs[m], 32, 64);
    }

    if (half == 1) {
#pragma unroll
        for (int m = 0; m < 2; ++m) {
#pragma unroll
            for (int d = 0; d < 4; ++d)
                *(floatx4*)&Ob[qs][m * 16 + lr][d * 16 + quad * 4] = o[m][d];
            Lb[qs][m * 16 + lr] = rs[m];
        }
    }
    __syncthreads();
    if (half == 0) {
        // write Y fragment-major over GLOBAL tokens: rowblk = (bh>>4)*128 + qb + m
        const long rb0 = (long)(bh >> 4) * 128 + qb;
        const int  hk  = (bh & 15) * DKH;           // k base for this head
#pragma unroll
        for (int m = 0; m < 2; ++m) {
            float l   = rs[m] + Lb[qs][m * 16 + lr];
            float inv = 1.f / l;
            long  rb  = rb0 + m;
#pragma unroll
            for (int d = 0; d < 4; ++d) {
                floatx4 ob = *(const floatx4*)&Ob[qs][m * 16 + lr][d * 16 + quad * 4];
                short4v y4;
#pragma unroll
                for (int r = 0; r < 4; ++r) y4[r] = bf16_of((o[m][d][r] + ob[r]) * inv);
                int kb = hk + d * 16 + quad * 4;
                long idx = (rb * 32 + (kb >> 5)) * 512
                         + (((kb >> 3) & 3) * 16 + lr) * 8 + (quad & 1) * 4;
                *(short4v*)(Y + idx) = y4;
            }
        }
    }
}

extern "C" void kernel_launch(void* const* d_in, const int* in_sizes, int n_in,
                              void* d_out, int out_size, void* d_ws, size_t ws_size,
                              hipStream_t stream) {
    const float* x  = (const float*)d_in[0];
    const float* Wq = (const float*)d_in[1];
    const float* bq = (const float*)d_in[2];
    const float* Wk = (const float*)d_in[3];
    const float* bk = (const float*)d_in[4];
    const float* Wv = (const float*)d_in[5];
    const float* bv = (const float*)d_in[6];
    const float* Wo = (const float*)d_in[7];
    const float* bo = (const float*)d_in[8];
    float* out = (float*)d_out;

    char* ws = (char*)d_ws;
    short* xf   = (short*)(ws);                      // x frag-major, 8MB; reused as Yf
    short* wqkf = (short*)(ws + (8L  << 20));        // [Wq;Wk] frag-major, 4MB
    short* wvf  = (short*)(ws + (12L << 20));        // Wv frag-major, 2MB
    short* wof  = (short*)(ws + (14L << 20));        // Wo frag-major, 2MB
    short* Qb   = (short*)(ws + (16L << 20));        // Qf, 8MB (pre-scaled)
    short* Kbuf = (short*)(ws + (24L << 20));        // Kf, 8MB
    short* Vtb  = (short*)(ws + (32L << 20));        // Vf, 8MB
    short* Yf   = xf;                                // reuse (x dead after QKV GEMM)

    cvt_frag<<<512, 256, 0, stream>>>(x, Wq, Wk, Wv, Wo, xf, wqkf, wvf, wof);

    gemm_qkv<<<768, 256, 0, stream>>>(xf, wqkf, wvf, bq, bk, bv, Qb, Kbuf, Vtb);
    attn_kernel<<<1024, 256, 0, stream>>>(Qb, Kbuf, Vtb, Yf);
    gemm_proj<<<512, 64, 0, stream>>>(Yf, wof, bo, out);
}

// Round 7
// 175.304 us; speedup vs baseline: 1.0208x; 1.0194x over previous
//
#include <hip/hip_runtime.h>
#include <hip/hip_bf16.h>

#define N_EMBD 1024
#define T_SEQ  2048
#define BATCH  2
#define NHEAD  16
#define DKH    64
#define MTOK   (BATCH * T_SEQ)   // 4096

typedef __attribute__((ext_vector_type(8))) short short8;   // 8 x bf16
typedef __attribute__((ext_vector_type(4))) short short4v;  // 4 x bf16
typedef __attribute__((ext_vector_type(4))) float floatx4;  // MFMA C/D

#define QSCALE 0.18033688011112042f   // 0.125 * log2(e), folded into Q

static __device__ __forceinline__ short bf16_of(float f) {
    union { float f; unsigned u; } x; x.f = f;
    unsigned r = (x.u + 0x7fff + ((x.u >> 16) & 1)) >> 16;
    return (short)r;
}

// Fragment-major layout for a row-major [R][1024] bf16 matrix:
//   elem (row, k) -> ((row>>4)*32 + (k>>5))*512 + (((k>>3)&3)*16 + (row&15))*8 + (k&7)
// i.e. one MFMA operand fragment (16 rows x 32 k) = 512 contiguous shorts,
// loadable as lane*16B fully-coalesced dwordx4.

// ---------------- fp32 -> bf16 fragment-major convert, all 5 tensors ----------------
__global__ __launch_bounds__(256) void cvt_frag(
    const float* __restrict__ x,  const float* __restrict__ Wq,
    const float* __restrict__ Wk, const float* __restrict__ Wv,
    const float* __restrict__ Wo,
    short* __restrict__ xf, short* __restrict__ wqkf,
    short* __restrict__ wvf, short* __restrict__ wof)
{
    int b = blockIdx.x;
    const float* src; short* dst; int srb, drb;
    if (b < 256)      { src = x;  dst = xf;   srb = b;       drb = srb; }
    else if (b < 320) { src = Wq; dst = wqkf; srb = b - 256; drb = srb; }
    else if (b < 384) { src = Wk; dst = wqkf; srb = b - 320; drb = srb + 64; }
    else if (b < 448) { src = Wv; dst = wvf;  srb = b - 384; drb = srb; }
    else              { src = Wo; dst = wof;  srb = b - 448; drb = srb; }

    const int row16 = threadIdx.x >> 4;          // 0..15
    const int kseg  = (threadIdx.x & 15) * 64;   // k base (64 elems per thread)
    const float* sp = src + ((long)srb * 16 + row16) * 1024 + kseg;
    short* dp       = dst + ((long)drb * 32 + (kseg >> 5)) * 512 + row16 * 8;

#pragma unroll
    for (int c = 0; c < 8; ++c) {
        float4 v0 = *(const float4*)(sp + c * 8);
        float4 v1 = *(const float4*)(sp + c * 8 + 4);
        short8 o;
        o[0] = bf16_of(v0.x); o[1] = bf16_of(v0.y); o[2] = bf16_of(v0.z); o[3] = bf16_of(v0.w);
        o[4] = bf16_of(v1.x); o[5] = bf16_of(v1.y); o[6] = bf16_of(v1.z); o[7] = bf16_of(v1.w);
        *(short8*)(dp + (c >> 2) * 512 + (c & 3) * 128) = o;
    }
}

// K-loop: per-wave 64x128 tile, register ping-pong prefetch, no LDS/barriers.
#define GEMM_KLOOP(Ab, Bb)                                                     \
    floatx4 acc[4][8] = {};                                                    \
    short8 a0[4], a1[4], b0[8], b1[8];                                         \
    _Pragma("unroll") for (int i = 0; i < 4; ++i)                              \
        a0[i] = *(const short8*)(Ab + (long)i * 32 * 512);                     \
    _Pragma("unroll") for (int j = 0; j < 8; ++j)                              \
        b0[j] = *(const short8*)(Bb + (long)j * 32 * 512);                     \
    for (int kc = 0; kc < 32; kc += 2) {                                       \
        _Pragma("unroll") for (int i = 0; i < 4; ++i)                          \
            a1[i] = *(const short8*)(Ab + ((long)i * 32 + kc + 1) * 512);      \
        _Pragma("unroll") for (int j = 0; j < 8; ++j)                          \
            b1[j] = *(const short8*)(Bb + ((long)j * 32 + kc + 1) * 512);      \
        _Pragma("unroll") for (int i = 0; i < 4; ++i)                          \
            _Pragma("unroll") for (int j = 0; j < 8; ++j)                      \
                acc[i][j] = __builtin_amdgcn_mfma_f32_16x16x32_bf16(           \
                    a0[i], b0[j], acc[i][j], 0, 0, 0);                         \
        if (kc + 2 < 32) {                                                     \
            _Pragma("unroll") for (int i = 0; i < 4; ++i)                      \
                a0[i] = *(const short8*)(Ab + ((long)i * 32 + kc + 2) * 512);  \
            _Pragma("unroll") for (int j = 0; j < 8; ++j)                      \
                b0[j] = *(const short8*)(Bb + ((long)j * 32 + kc + 2) * 512);  \
        }                                                                      \
        _Pragma("unroll") for (int i = 0; i < 4; ++i)                          \
            _Pragma("unroll") for (int j = 0; j < 8; ++j)                      \
                acc[i][j] = __builtin_amdgcn_mfma_f32_16x16x32_bf16(           \
                    a1[i], b1[j], acc[i][j], 0, 0, 0);                         \
    }

// ---------------- QKV GEMM: 1536 single-wave blocks, no LDS (R0) ----------------
// wid < 1024: Q/K transposed (rows = Wqk feature 64, cols = token 128)
// wid >= 1024: V normal (rows = token 64, cols = Wv feature 128)
__global__ __launch_bounds__(64, 2) void gemm_qkv(
    const short* __restrict__ xf, const short* __restrict__ wqkf,
    const short* __restrict__ wvf,
    const float* __restrict__ bq, const float* __restrict__ bk, const float* __restrict__ bv,
    short* __restrict__ outQ, short* __restrict__ outK, short* __restrict__ outV)
{
    const int lane = threadIdx.x & 63;
    const int quad = lane >> 4, lr = lane & 15;
    const int wid  = blockIdx.x;
    const bool isQK = wid < 1024;
    int mw, nw;
    const short *Af, *Bf;
    if (isQK) { mw = (wid >> 5) * 64;          nw = (wid & 31) * 128; Af = wqkf; Bf = xf; }
    else      { int v = wid - 1024;
                mw = (v >> 3) * 64;            nw = (v & 7) * 128;    Af = xf;   Bf = wvf; }

    const short* Ab = Af + (long)(mw >> 4) * 32 * 512 + lane * 8;
    const short* Bb = Bf + (long)(nw >> 4) * 32 * 512 + lane * 8;

    GEMM_KLOOP(Ab, Bb)

    if (isQK) {
#pragma unroll
        for (int i = 0; i < 4; ++i) {
#pragma unroll
            for (int j = 0; j < 8; ++j) {
                int f0  = mw + i * 16 + quad * 4;      // feature of [Wq;Wk]
                int t   = nw + j * 16 + lr;            // global token
                int tb  = t & 2047;
                int sel = f0 >> 10;                    // 0=Q, 1=K
                int fb  = f0 & 1023;
                int h   = fb >> 6, d0 = fb & 63;
                long bh = (long)(t >> 11) * NHEAD + h;
                float4 bias = *(const float4*)((sel ? bk : bq) + fb);
                short4v y;
#pragma unroll
                for (int r = 0; r < 4; ++r) {
                    float v = acc[i][j][r] + (&bias.x)[r];
                    if (sel == 0) v *= QSCALE;
                    y[r] = bf16_of(v);
                }
                long idx = ((bh * 128 + (tb >> 4)) * 2 + (d0 >> 5)) * 512
                         + (((d0 >> 3) & 3) * 16 + (tb & 15)) * 8 + (d0 & 7);
                *(short4v*)((sel ? outK : outQ) + idx) = y;
            }
        }
    } else {
#pragma unroll
        for (int i = 0; i < 4; ++i) {
#pragma unroll
            for (int j = 0; j < 8; ++j) {
                int t0 = mw + i * 16 + quad * 4;       // global token base
                int tb = t0 & 2047;
                int d  = nw + j * 16 + lr;             // Wv feature
                int h  = d >> 6, dblk = (d >> 4) & 3;
                long bh = (long)(t0 >> 11) * NHEAD + h;
                float bias = bv[d];
                short4v y;
#pragma unroll
                for (int r = 0; r < 4; ++r) y[r] = bf16_of(acc[i][j][r] + bias);
                long idx = ((bh * 64 + (tb >> 5)) * 4 + dblk) * 512
                         + lane * 8 + (i & 1) * 4;
                *(short4v*)(outV + idx) = y;
            }
        }
    }
}

// ---------------- output projection: 512 single-wave blocks, no LDS (R0) ----------------
// Transposed (rows = out-feature 64, cols = token 128); float4 stores.
__global__ __launch_bounds__(64, 2) void gemm_proj(
    const short* __restrict__ Yf, const short* __restrict__ wof,
    const float* __restrict__ bo, float* __restrict__ out)
{
    const int lane = threadIdx.x & 63;
    const int quad = lane >> 4, lr = lane & 15;
    const int wid  = blockIdx.x;
    const int mw   = (wid >> 5) * 64;     // out-feature
    const int nw   = (wid & 31) * 128;    // token

    const short* Ab = wof + (long)(mw >> 4) * 32 * 512 + lane * 8;
    const short* Bb = Yf  + (long)(nw >> 4) * 32 * 512 + lane * 8;

    GEMM_KLOOP(Ab, Bb)

#pragma unroll
    for (int i = 0; i < 4; ++i) {
#pragma unroll
        for (int j = 0; j < 8; ++j) {
            int  f0 = mw + i * 16 + quad * 4;
            long t  = nw + j * 16 + lr;
            float4 b4 = *(const float4*)(bo + f0);
            float4 o4;
            o4.x = acc[i][j][0] + b4.x;
            o4.y = acc[i][j][1] + b4.y;
            o4.z = acc[i][j][2] + b4.z;
            o4.w = acc[i][j][3] + b4.w;
            *(float4*)(out + t * N_EMBD + f0) = o4;
        }
    }
}

// ---------------- flash attention (R0 core) + V prefetch; NO setprio ----------------
__global__ __launch_bounds__(256) void attn_kernel(
    const short* __restrict__ Qf, const short* __restrict__ Kf,
    const short* __restrict__ Vf, short* __restrict__ Y)
{
    __shared__ float Ob[2][32][68];
    __shared__ float Lb[2][32];

    const int tid  = threadIdx.x;
    const int w    = tid >> 6, lane = tid & 63;
    const int quad = lane >> 4, lr = lane & 15;
    const int qs   = w & 1, half = w >> 1;

    const int id = blockIdx.x;
    const int qt = 31 - (id >> 5);
    const int bh = id & 31;

    const short* Qp = Qf + (long)bh * 131072;
    const short* Kp = Kf + (long)bh * 131072;
    const short* Vp = Vf + (long)bh * 131072;

    const int qrb = qt * 64 + qs * 32;
    const int qb  = qrb >> 4;

    short8 qfv[2][2];
#pragma unroll
    for (int m = 0; m < 2; ++m)
#pragma unroll
        for (int c = 0; c < 2; ++c)
            qfv[m][c] = *(const short8*)(Qp + (long)(((qb + m) * 2 + c) * 512) + lane * 8);

    floatx4 o[2][4] = {};
    float rs[2] = {0.f, 0.f};

    const int S_tot = 2 * qt + qs + 1;
    const int h0 = (S_tot + 1) >> 1;
    const int sb = half ? h0 : 0;
    const int se = half ? S_tot : h0;

    short8 kbn[2][2];
    short8 vbn[4];
    if (sb < se) {
#pragma unroll
        for (int blk = 0; blk < 2; ++blk)
#pragma unroll
            for (int c = 0; c < 2; ++c)
                kbn[blk][c] = *(const short8*)(Kp + (long)(((sb * 2 + blk) * 2 + c) * 512) + lane * 8);
#pragma unroll
        for (int d = 0; d < 4; ++d)
            vbn[d] = *(const short8*)(Vp + (long)((sb * 4 + d) * 512) + lane * 8);
    }

    for (int s = sb; s < se; ++s) {
        short8 ka[2][2];
        short8 va[4];
#pragma unroll
        for (int blk = 0; blk < 2; ++blk)
#pragma unroll
            for (int c = 0; c < 2; ++c) ka[blk][c] = kbn[blk][c];
#pragma unroll
        for (int d = 0; d < 4; ++d) va[d] = vbn[d];

        if (s + 1 < se) {
#pragma unroll
            for (int blk = 0; blk < 2; ++blk)
#pragma unroll
                for (int c = 0; c < 2; ++c)
                    kbn[blk][c] = *(const short8*)(Kp + (long)((((s + 1) * 2 + blk) * 2 + c) * 512) + lane * 8);
#pragma unroll
            for (int d = 0; d < 4; ++d)
                vbn[d] = *(const short8*)(Vp + (long)(((s + 1) * 4 + d) * 512) + lane * 8);
        }

        floatx4 sc[2][2];
#pragma unroll
        for (int m = 0; m < 2; ++m)
#pragma unroll
            for (int blk = 0; blk < 2; ++blk) {
                floatx4 z = {};
                z = __builtin_amdgcn_mfma_f32_16x16x32_bf16(ka[blk][0], qfv[m][0], z, 0, 0, 0);
                z = __builtin_amdgcn_mfma_f32_16x16x32_bf16(ka[blk][1], qfv[m][1], z, 0, 0, 0);
                sc[m][blk] = z;
            }

        if (s == S_tot - 1) {
            const int k0 = s * 32;
#pragma unroll
            for (int m = 0; m < 2; ++m)
#pragma unroll
                for (int blk = 0; blk < 2; ++blk)
#pragma unroll
                    for (int r = 0; r < 4; ++r) {
                        int key = k0 + blk * 16 + quad * 4 + r;
                        if (key > qrb + m * 16 + lr) sc[m][blk][r] = -INFINITY;
                    }
        }

        short8 pa[2];
#pragma unroll
        for (int m = 0; m < 2; ++m) {
            union { short8 v; short e[8]; } pu;
#pragma unroll
            for (int blk = 0; blk < 2; ++blk)
#pragma unroll
                for (int r = 0; r < 4; ++r) {
                    float p = __builtin_amdgcn_exp2f(sc[m][blk][r]);
                    rs[m] += p;
                    union { float f; unsigned u; } cc; cc.f = p;
                    pu.e[blk * 4 + r] = (short)((cc.u + 0x8000u) >> 16);
                }
            pa[m] = pu.v;
        }

#pragma unroll
        for (int m = 0; m < 2; ++m)
#pragma unroll
            for (int d = 0; d < 4; ++d)
                o[m][d] = __builtin_amdgcn_mfma_f32_16x16x32_bf16(va[d], pa[m], o[m][d], 0, 0, 0);
    }

#pragma unroll
    for (int m = 0; m < 2; ++m) {
        rs[m] += __shfl_xor(rs[m], 16, 64);
        rs[m] += __shfl_xor(rs[m], 32, 64);
    }

    if (half == 1) {
#pragma unroll
        for (int m = 0; m < 2; ++m) {
#pragma unroll
            for (int d = 0; d < 4; ++d)
                *(floatx4*)&Ob[qs][m * 16 + lr][d * 16 + quad * 4] = o[m][d];
            Lb[qs][m * 16 + lr] = rs[m];
        }
    }
    __syncthreads();
    if (half == 0) {
        // write Y fragment-major over GLOBAL tokens: rowblk = (bh>>4)*128 + qb + m
        const long rb0 = (long)(bh >> 4) * 128 + qb;
        const int  hk  = (bh & 15) * DKH;           // k base for this head
#pragma unroll
        for (int m = 0; m < 2; ++m) {
            float l   = rs[m] + Lb[qs][m * 16 + lr];
            float inv = 1.f / l;
            long  rb  = rb0 + m;
#pragma unroll
            for (int d = 0; d < 4; ++d) {
                floatx4 ob = *(const floatx4*)&Ob[qs][m * 16 + lr][d * 16 + quad * 4];
                short4v y4;
#pragma unroll
                for (int r = 0; r < 4; ++r) y4[r] = bf16_of((o[m][d][r] + ob[r]) * inv);
                int kb = hk + d * 16 + quad * 4;
                long idx = (rb * 32 + (kb >> 5)) * 512
                         + (((kb >> 3) & 3) * 16 + lr) * 8 + (quad & 1) * 4;
                *(short4v*)(Y + idx) = y4;
            }
        }
    }
}

extern "C" void kernel_launch(void* const* d_in, const int* in_sizes, int n_in,
                              void* d_out, int out_size, void* d_ws, size_t ws_size,
                              hipStream_t stream) {
    const float* x  = (const float*)d_in[0];
    const float* Wq = (const float*)d_in[1];
    const float* bq = (const float*)d_in[2];
    const float* Wk = (const float*)d_in[3];
    const float* bk = (const float*)d_in[4];
    const float* Wv = (const float*)d_in[5];
    const float* bv = (const float*)d_in[6];
    const float* Wo = (const float*)d_in[7];
    const float* bo = (const float*)d_in[8];
    float* out = (float*)d_out;

    char* ws = (char*)d_ws;
    short* xf   = (short*)(ws);                      // x frag-major, 8MB; reused as Yf
    short* wqkf = (short*)(ws + (8L  << 20));        // [Wq;Wk] frag-major, 4MB
    short* wvf  = (short*)(ws + (12L << 20));        // Wv frag-major, 2MB
    short* wof  = (short*)(ws + (14L << 20));        // Wo frag-major, 2MB
    short* Qb   = (short*)(ws + (16L << 20));        // Qf, 8MB (pre-scaled)
    short* Kbuf = (short*)(ws + (24L << 20));        // Kf, 8MB
    short* Vtb  = (short*)(ws + (32L << 20));        // Vf, 8MB
    short* Yf   = xf;                                // reuse (x dead after QKV GEMM)

    cvt_frag<<<512, 256, 0, stream>>>(x, Wq, Wk, Wv, Wo, xf, wqkf, wvf, wof);

    gemm_qkv<<<1536, 64, 0, stream>>>(xf, wqkf, wvf, bq, bk, bv, Qb, Kbuf, Vtb);
    attn_kernel<<<1024, 256, 0, stream>>>(Qb, Kbuf, Vtb, Yf);
    gemm_proj<<<512, 64, 0, stream>>>(Yf, wof, bo, out);
}

// Round 8
// 171.638 us; speedup vs baseline: 1.0425x; 1.0214x over previous
//
#include <hip/hip_runtime.h>
#include <hip/hip_bf16.h>

#define N_EMBD 1024
#define T_SEQ  2048
#define BATCH  2
#define NHEAD  16
#define DKH    64
#define MTOK   (BATCH * T_SEQ)   // 4096

typedef __attribute__((ext_vector_type(8))) short short8;   // 8 x bf16
typedef __attribute__((ext_vector_type(4))) short short4v;  // 4 x bf16
typedef __attribute__((ext_vector_type(4))) float floatx4;  // MFMA C/D

#define QSCALE 0.18033688011112042f   // 0.125 * log2(e), folded into Q

static __device__ __forceinline__ short bf16_of(float f) {
    union { float f; unsigned u; } x; x.f = f;
    unsigned r = (x.u + 0x7fff + ((x.u >> 16) & 1)) >> 16;
    return (short)r;
}

// Fragment-major layout for a row-major [R][1024] bf16 matrix:
//   elem (row, k) -> ((row>>4)*32 + (k>>5))*512 + (((k>>3)&3)*16 + (row&15))*8 + (k&7)
// i.e. one MFMA operand fragment (16 rows x 32 k) = 512 contiguous shorts,
// loadable as lane*16B fully-coalesced dwordx4.

// ---------------- fp32 -> bf16 fragment-major convert, all 5 tensors ----------------
// 512 blocks: [0,256) x ; [256,320) Wq ; [320,384) Wk (dst rows +1024) ;
// [384,448) Wv ; [448,512) Wo.  Block = one 16-row rowblk x 1024 k.
__global__ __launch_bounds__(256) void cvt_frag(
    const float* __restrict__ x,  const float* __restrict__ Wq,
    const float* __restrict__ Wk, const float* __restrict__ Wv,
    const float* __restrict__ Wo,
    short* __restrict__ xf, short* __restrict__ wqkf,
    short* __restrict__ wvf, short* __restrict__ wof)
{
    int b = blockIdx.x;
    const float* src; short* dst; int srb, drb;
    if (b < 256)      { src = x;  dst = xf;   srb = b;       drb = srb; }
    else if (b < 320) { src = Wq; dst = wqkf; srb = b - 256; drb = srb; }
    else if (b < 384) { src = Wk; dst = wqkf; srb = b - 320; drb = srb + 64; }
    else if (b < 448) { src = Wv; dst = wvf;  srb = b - 384; drb = srb; }
    else              { src = Wo; dst = wof;  srb = b - 448; drb = srb; }

    const int row16 = threadIdx.x >> 4;          // 0..15
    const int kseg  = (threadIdx.x & 15) * 64;   // k base (64 elems per thread)
    const float* sp = src + ((long)srb * 16 + row16) * 1024 + kseg;
    short* dp       = dst + ((long)drb * 32 + (kseg >> 5)) * 512 + row16 * 8;

#pragma unroll
    for (int c = 0; c < 8; ++c) {
        float4 v0 = *(const float4*)(sp + c * 8);
        float4 v1 = *(const float4*)(sp + c * 8 + 4);
        short8 o;
        o[0] = bf16_of(v0.x); o[1] = bf16_of(v0.y); o[2] = bf16_of(v0.z); o[3] = bf16_of(v0.w);
        o[4] = bf16_of(v1.x); o[5] = bf16_of(v1.y); o[6] = bf16_of(v1.z); o[7] = bf16_of(v1.w);
        *(short8*)(dp + (c >> 2) * 512 + (c & 3) * 128) = o;
    }
}

// K-loop: per-wave 64x128 tile, register ping-pong prefetch, no LDS/barriers.
#define GEMM_KLOOP(Ab, Bb)                                                     \
    floatx4 acc[4][8] = {};                                                    \
    short8 a0[4], a1[4], b0[8], b1[8];                                         \
    _Pragma("unroll") for (int i = 0; i < 4; ++i)                              \
        a0[i] = *(const short8*)(Ab + (long)i * 32 * 512);                     \
    _Pragma("unroll") for (int j = 0; j < 8; ++j)                              \
        b0[j] = *(const short8*)(Bb + (long)j * 32 * 512);                     \
    for (int kc = 0; kc < 32; kc += 2) {                                       \
        _Pragma("unroll") for (int i = 0; i < 4; ++i)                          \
            a1[i] = *(const short8*)(Ab + ((long)i * 32 + kc + 1) * 512);      \
        _Pragma("unroll") for (int j = 0; j < 8; ++j)                          \
            b1[j] = *(const short8*)(Bb + ((long)j * 32 + kc + 1) * 512);      \
        _Pragma("unroll") for (int i = 0; i < 4; ++i)                          \
            _Pragma("unroll") for (int j = 0; j < 8; ++j)                      \
                acc[i][j] = __builtin_amdgcn_mfma_f32_16x16x32_bf16(           \
                    a0[i], b0[j], acc[i][j], 0, 0, 0);                         \
        if (kc + 2 < 32) {                                                     \
            _Pragma("unroll") for (int i = 0; i < 4; ++i)                      \
                a0[i] = *(const short8*)(Ab + ((long)i * 32 + kc + 2) * 512);  \
            _Pragma("unroll") for (int j = 0; j < 8; ++j)                      \
                b0[j] = *(const short8*)(Bb + ((long)j * 32 + kc + 2) * 512);  \
        }                                                                      \
        _Pragma("unroll") for (int i = 0; i < 4; ++i)                          \
            _Pragma("unroll") for (int j = 0; j < 8; ++j)                      \
                acc[i][j] = __builtin_amdgcn_mfma_f32_16x16x32_bf16(           \
                    a1[i], b1[j], acc[i][j], 0, 0, 0);                         \
    }

// ---------------- QKV GEMM: 1536 single-wave blocks, no LDS ----------------
// wid < 1024: Q/K transposed (rows = Wqk feature 64, cols = token 128)
// wid >= 1024: V normal (rows = token 64, cols = Wv feature 128)
__global__ __launch_bounds__(64, 2) void gemm_qkv(
    const short* __restrict__ xf, const short* __restrict__ wqkf,
    const short* __restrict__ wvf,
    const float* __restrict__ bq, const float* __restrict__ bk, const float* __restrict__ bv,
    short* __restrict__ outQ, short* __restrict__ outK, short* __restrict__ outV)
{
    const int lane = threadIdx.x & 63;
    const int quad = lane >> 4, lr = lane & 15;
    const int wid  = blockIdx.x;
    const bool isQK = wid < 1024;
    int mw, nw;
    const short *Af, *Bf;
    if (isQK) { mw = (wid >> 5) * 64;          nw = (wid & 31) * 128; Af = wqkf; Bf = xf; }
    else      { int v = wid - 1024;
                mw = (v >> 3) * 64;            nw = (v & 7) * 128;    Af = xf;   Bf = wvf; }

    const short* Ab = Af + (long)(mw >> 4) * 32 * 512 + lane * 8;
    const short* Bb = Bf + (long)(nw >> 4) * 32 * 512 + lane * 8;

    GEMM_KLOOP(Ab, Bb)

    if (isQK) {
#pragma unroll
        for (int i = 0; i < 4; ++i) {
#pragma unroll
            for (int j = 0; j < 8; ++j) {
                int f0  = mw + i * 16 + quad * 4;      // feature of [Wq;Wk]
                int t   = nw + j * 16 + lr;            // global token
                int tb  = t & 2047;
                int sel = f0 >> 10;                    // 0=Q, 1=K
                int fb  = f0 & 1023;
                int h   = fb >> 6, d0 = fb & 63;
                long bh = (long)(t >> 11) * NHEAD + h;
                float4 bias = *(const float4*)((sel ? bk : bq) + fb);
                short4v y;
#pragma unroll
                for (int r = 0; r < 4; ++r) {
                    float v = acc[i][j][r] + (&bias.x)[r];
                    if (sel == 0) v *= QSCALE;
                    y[r] = bf16_of(v);
                }
                long idx = ((bh * 128 + (tb >> 4)) * 2 + (d0 >> 5)) * 512
                         + (((d0 >> 3) & 3) * 16 + (tb & 15)) * 8 + (d0 & 7);
                *(short4v*)((sel ? outK : outQ) + idx) = y;
            }
        }
    } else {
#pragma unroll
        for (int i = 0; i < 4; ++i) {
#pragma unroll
            for (int j = 0; j < 8; ++j) {
                int t0 = mw + i * 16 + quad * 4;       // global token base
                int tb = t0 & 2047;
                int d  = nw + j * 16 + lr;             // Wv feature
                int h  = d >> 6, dblk = (d >> 4) & 3;
                long bh = (long)(t0 >> 11) * NHEAD + h;
                float bias = bv[d];
                short4v y;
#pragma unroll
                for (int r = 0; r < 4; ++r) y[r] = bf16_of(acc[i][j][r] + bias);
                long idx = ((bh * 64 + (tb >> 5)) * 4 + dblk) * 512
                         + lane * 8 + (i & 1) * 4;
                *(short4v*)(outV + idx) = y;
            }
        }
    }
}

// ---------------- output projection: 512 single-wave blocks, no LDS ----------------
// Transposed (rows = out-feature 64, cols = token 128); float4 stores.
__global__ __launch_bounds__(64, 2) void gemm_proj(
    const short* __restrict__ Yf, const short* __restrict__ wof,
    const float* __restrict__ bo, float* __restrict__ out)
{
    const int lane = threadIdx.x & 63;
    const int quad = lane >> 4, lr = lane & 15;
    const int wid  = blockIdx.x;
    const int mw   = (wid >> 5) * 64;     // out-feature
    const int nw   = (wid & 31) * 128;    // token

    const short* Ab = wof + (long)(mw >> 4) * 32 * 512 + lane * 8;
    const short* Bb = Yf  + (long)(nw >> 4) * 32 * 512 + lane * 8;

    GEMM_KLOOP(Ab, Bb)

#pragma unroll
    for (int i = 0; i < 4; ++i) {
#pragma unroll
        for (int j = 0; j < 8; ++j) {
            int  f0 = mw + i * 16 + quad * 4;
            long t  = nw + j * 16 + lr;
            float4 b4 = *(const float4*)(bo + f0);
            float4 o4;
            o4.x = acc[i][j][0] + b4.x;
            o4.y = acc[i][j][1] + b4.y;
            o4.z = acc[i][j][2] + b4.z;
            o4.w = acc[i][j][3] + b4.w;
            *(float4*)(out + t * N_EMBD + f0) = o4;
        }
    }
}

// ---------------- flash attention (unchanged core); epilogue -> fragment-major Y ----------------
__global__ __launch_bounds__(256) void attn_kernel(
    const short* __restrict__ Qf, const short* __restrict__ Kf,
    const short* __restrict__ Vf, short* __restrict__ Y)
{
    __shared__ float Ob[2][32][68];
    __shared__ float Lb[2][32];

    const int tid  = threadIdx.x;
    const int w    = tid >> 6, lane = tid & 63;
    const int quad = lane >> 4, lr = lane & 15;
    const int qs   = w & 1, half = w >> 1;

    const int id = blockIdx.x;
    const int qt = 31 - (id >> 5);
    const int bh = id & 31;

    const short* Qp = Qf + (long)bh * 131072;
    const short* Kp = Kf + (long)bh * 131072;
    const short* Vp = Vf + (long)bh * 131072;

    const int qrb = qt * 64 + qs * 32;
    const int qb  = qrb >> 4;

    short8 qfv[2][2];
#pragma unroll
    for (int m = 0; m < 2; ++m)
#pragma unroll
        for (int c = 0; c < 2; ++c)
            qfv[m][c] = *(const short8*)(Qp + (long)(((qb + m) * 2 + c) * 512) + lane * 8);

    floatx4 o[2][4] = {};
    float rs[2] = {0.f, 0.f};

    const int S_tot = 2 * qt + qs + 1;
    const int h0 = (S_tot + 1) >> 1;
    const int sb = half ? h0 : 0;
    const int se = half ? S_tot : h0;

    short8 kbn[2][2];
    if (sb < se) {
#pragma unroll
        for (int blk = 0; blk < 2; ++blk)
#pragma unroll
            for (int c = 0; c < 2; ++c)
                kbn[blk][c] = *(const short8*)(Kp + (long)(((sb * 2 + blk) * 2 + c) * 512) + lane * 8);
    }

    for (int s = sb; s < se; ++s) {
        short8 ka[2][2];
#pragma unroll
        for (int blk = 0; blk < 2; ++blk)
#pragma unroll
            for (int c = 0; c < 2; ++c) ka[blk][c] = kbn[blk][c];
        if (s + 1 < se) {
#pragma unroll
            for (int blk = 0; blk < 2; ++blk)
#pragma unroll
                for (int c = 0; c < 2; ++c)
                    kbn[blk][c] = *(const short8*)(Kp + (long)((((s + 1) * 2 + blk) * 2 + c) * 512) + lane * 8);
        }
        short8 va[4];
#pragma unroll
        for (int d = 0; d < 4; ++d)
            va[d] = *(const short8*)(Vp + (long)((s * 4 + d) * 512) + lane * 8);

        floatx4 sc[2][2];
#pragma unroll
        for (int m = 0; m < 2; ++m)
#pragma unroll
            for (int blk = 0; blk < 2; ++blk) {
                floatx4 z = {};
                z = __builtin_amdgcn_mfma_f32_16x16x32_bf16(ka[blk][0], qfv[m][0], z, 0, 0, 0);
                z = __builtin_amdgcn_mfma_f32_16x16x32_bf16(ka[blk][1], qfv[m][1], z, 0, 0, 0);
                sc[m][blk] = z;
            }

        if (s == S_tot - 1) {
            const int k0 = s * 32;
#pragma unroll
            for (int m = 0; m < 2; ++m)
#pragma unroll
                for (int blk = 0; blk < 2; ++blk)
#pragma unroll
                    for (int r = 0; r < 4; ++r) {
                        int key = k0 + blk * 16 + quad * 4 + r;
                        if (key > qrb + m * 16 + lr) sc[m][blk][r] = -INFINITY;
                    }
        }

        short8 pa[2];
#pragma unroll
        for (int m = 0; m < 2; ++m) {
            union { short8 v; short e[8]; } pu;
#pragma unroll
            for (int blk = 0; blk < 2; ++blk)
#pragma unroll
                for (int r = 0; r < 4; ++r) {
                    float p = __builtin_amdgcn_exp2f(sc[m][blk][r]);
                    rs[m] += p;
                    union { float f; unsigned u; } cc; cc.f = p;
                    pu.e[blk * 4 + r] = (short)((cc.u + 0x8000u) >> 16);
                }
            pa[m] = pu.v;
        }

#pragma unroll
        for (int m = 0; m < 2; ++m)
#pragma unroll
            for (int d = 0; d < 4; ++d)
                o[m][d] = __builtin_amdgcn_mfma_f32_16x16x32_bf16(va[d], pa[m], o[m][d], 0, 0, 0);
    }

#pragma unroll
    for (int m = 0; m < 2; ++m) {
        rs[m] += __shfl_xor(rs[m], 16, 64);
        rs[m] += __shfl_xor(rs[m], 32, 64);
    }

    if (half == 1) {
#pragma unroll
        for (int m = 0; m < 2; ++m) {
#pragma unroll
            for (int d = 0; d < 4; ++d)
                *(floatx4*)&Ob[qs][m * 16 + lr][d * 16 + quad * 4] = o[m][d];
            Lb[qs][m * 16 + lr] = rs[m];
        }
    }
    __syncthreads();
    if (half == 0) {
        // write Y fragment-major over GLOBAL tokens: rowblk = (bh>>4)*128 + qb + m
        const long rb0 = (long)(bh >> 4) * 128 + qb;
        const int  hk  = (bh & 15) * DKH;           // k base for this head
#pragma unroll
        for (int m = 0; m < 2; ++m) {
            float l   = rs[m] + Lb[qs][m * 16 + lr];
            float inv = 1.f / l;
            long  rb  = rb0 + m;
#pragma unroll
            for (int d = 0; d < 4; ++d) {
                floatx4 ob = *(const floatx4*)&Ob[qs][m * 16 + lr][d * 16 + quad * 4];
                short4v y4;
#pragma unroll
                for (int r = 0; r < 4; ++r) y4[r] = bf16_of((o[m][d][r] + ob[r]) * inv);
                int kb = hk + d * 16 + quad * 4;
                long idx = (rb * 32 + (kb >> 5)) * 512
                         + (((kb >> 3) & 3) * 16 + lr) * 8 + (quad & 1) * 4;
                *(short4v*)(Y + idx) = y4;
            }
        }
    }
}

extern "C" void kernel_launch(void* const* d_in, const int* in_sizes, int n_in,
                              void* d_out, int out_size, void* d_ws, size_t ws_size,
                              hipStream_t stream) {
    const float* x  = (const float*)d_in[0];
    const float* Wq = (const float*)d_in[1];
    const float* bq = (const float*)d_in[2];
    const float* Wk = (const float*)d_in[3];
    const float* bk = (const float*)d_in[4];
    const float* Wv = (const float*)d_in[5];
    const float* bv = (const float*)d_in[6];
    const float* Wo = (const float*)d_in[7];
    const float* bo = (const float*)d_in[8];
    float* out = (float*)d_out;

    char* ws = (char*)d_ws;
    short* xf   = (short*)(ws);                      // x frag-major, 8MB; reused as Yf
    short* wqkf = (short*)(ws + (8L  << 20));        // [Wq;Wk] frag-major, 4MB
    short* wvf  = (short*)(ws + (12L << 20));        // Wv frag-major, 2MB
    short* wof  = (short*)(ws + (14L << 20));        // Wo frag-major, 2MB
    short* Qb   = (short*)(ws + (16L << 20));        // Qf, 8MB (pre-scaled)
    short* Kbuf = (short*)(ws + (24L << 20));        // Kf, 8MB
    short* Vtb  = (short*)(ws + (32L << 20));        // Vf, 8MB
    short* Yf   = xf;                                // reuse (x dead after QKV GEMM)

    cvt_frag<<<512, 256, 0, stream>>>(x, Wq, Wk, Wv, Wo, xf, wqkf, wvf, wof);

    gemm_qkv<<<1536, 64, 0, stream>>>(xf, wqkf, wvf, bq, bk, bv, Qb, Kbuf, Vtb);
    attn_kernel<<<1024, 256, 0, stream>>>(Qb, Kbuf, Vtb, Yf);
    gemm_proj<<<512, 64, 0, stream>>>(Yf, wof, bo, out);
}